// Round 8
// baseline (23949.806 us; speedup 1.0000x reference)
//
#include <hip/hip_runtime.h>

#define UNITS   2048
#define IN_DIM  128
#define T_STEPS 4096
#define NBLK    64
#define TPB     1024
#define BROWS   32    // rows per block
#define GROWS   8     // rows per thread-group
#define KCH     8     // cols per thread
#define CSTR    256   // col stride between a thread's cols
#define PCH     16    // units per poller thread

typedef unsigned int u32;
typedef u32 u32x4 __attribute__((ext_vector_type(4)));

// Re-zero comm words each call: tag 0 never matches (first polled tag is 1).
__global__ void esn_init(u32* __restrict__ buf) {
    int i = blockIdx.x * blockDim.x + threadIdx.x;
    if (i < 2 * UNITS) buf[i] = 0u;
}

template <int CTRL>
__device__ __forceinline__ float dpp_add(float x) {
    int y = __builtin_amdgcn_update_dpp(0, __float_as_int(x), CTRL, 0xF, 0xF, true);
    return x + __int_as_float(y);
}

__device__ __forceinline__ u32 orx4(const u32x4 v, u32 tg) {
    return (v[0] ^ tg) | (v[1] ^ tg) | (v[2] ^ tg) | (v[3] ^ tg);
}

// issue one 64B poll set (4 x dwordx4)
#define ISSUE(R0, R1, R2, R3)                                         \
    asm volatile(                                                     \
        "global_load_dwordx4 %0, %4, off sc0 sc1\n\t"                 \
        "global_load_dwordx4 %1, %4, off offset:16 sc0 sc1\n\t"       \
        "global_load_dwordx4 %2, %4, off offset:32 sc0 sc1\n\t"       \
        "global_load_dwordx4 %3, %4, off offset:48 sc0 sc1"           \
        : "=v"(R0), "=v"(R1), "=v"(R2), "=v"(R3) : "v"(pp) : "memory")

// wait for the OLDER set (4 newer still in flight); "+v" pins reg deps
#define WAIT4(R0, R1, R2, R3)                                         \
    asm volatile("s_waitcnt vmcnt(4)"                                 \
        : "+v"(R0), "+v"(R1), "+v"(R2), "+v"(R3) :: "memory")

// deposit 16 units: buffer slot p*16+i holds unit p+128*i -> lane-stride-4B LDS
#define DEP(R0, R1, R2, R3)                                           \
    do {                                                              \
        sv_lds[pnx][p +    0] = __uint_as_float(R0[0] << 16);         \
        sv_lds[pnx][p +  128] = __uint_as_float(R0[1] << 16);         \
        sv_lds[pnx][p +  256] = __uint_as_float(R0[2] << 16);         \
        sv_lds[pnx][p +  384] = __uint_as_float(R0[3] << 16);         \
        sv_lds[pnx][p +  512] = __uint_as_float(R1[0] << 16);         \
        sv_lds[pnx][p +  640] = __uint_as_float(R1[1] << 16);         \
        sv_lds[pnx][p +  768] = __uint_as_float(R1[2] << 16);         \
        sv_lds[pnx][p +  896] = __uint_as_float(R1[3] << 16);         \
        sv_lds[pnx][p + 1024] = __uint_as_float(R2[0] << 16);         \
        sv_lds[pnx][p + 1152] = __uint_as_float(R2[1] << 16);         \
        sv_lds[pnx][p + 1280] = __uint_as_float(R2[2] << 16);         \
        sv_lds[pnx][p + 1408] = __uint_as_float(R2[3] << 16);         \
        sv_lds[pnx][p + 1536] = __uint_as_float(R3[0] << 16);         \
        sv_lds[pnx][p + 1664] = __uint_as_float(R3[1] << 16);         \
        sv_lds[pnx][p + 1792] = __uint_as_float(R3[2] << 16);         \
        sv_lds[pnx][p + 1920] = __uint_as_float(R3[3] << 16);         \
    } while (0)

__global__ void __launch_bounds__(TPB, 4) esn_step(
    const float* __restrict__ inp,   // [4096][128]
    const float* __restrict__ s0,    // [2048]
    const float* __restrict__ W,     // [2048][2048] row-major
    const float* __restrict__ Win,   // [2048][128]
    float* __restrict__ out,         // [4096*2048 + 2048]
    u32* __restrict__ buf)           // [2][2048] packed (tag16|bf16) words
{
    const int b    = blockIdx.x;
    const int tid  = threadIdx.x;
    const int c    = tid & 255;      // col id: this thread's cols are c + 256*j
    const int g    = tid >> 8;       // row group 0..3
    const int lane = tid & 63;
    const int wv   = tid >> 6;       // wave 0..15

    // ---- W fragment: rows row0..row0+7, cols c+256*j ----
    const int row0 = b * BROWS + g * GROWS;
    float w[GROWS][KCH];
    #pragma unroll
    for (int r = 0; r < GROWS; ++r) {
        const float* wp = W + (size_t)(row0 + r) * UNITS + c;
        #pragma unroll
        for (int j = 0; j < KCH; ++j) w[r][j] = wp[j * CSTR];
    }
    float winv[GROWS];
    #pragma unroll
    for (int r = 0; r < GROWS; ++r) winv[r] = 0.f;
    if (c < IN_DIM) {
        #pragma unroll
        for (int r = 0; r < GROWS; ++r)
            winv[r] = Win[(size_t)(row0 + r) * IN_DIM + c];
    }

    // roles: waves 0-1 poll; wave 2 lanes 0-31 finalize
    const bool isPoller = (wv < 2);
    const bool isFin    = (wv == 2) && (lane < BROWS);
    const int  p        = tid;       // poller id 0..127 (valid when isPoller)
    float s_old = isFin ? s0[b * BROWS + lane] : 0.f;

    __shared__ float sv_lds[2][UNITS];        // parity-buffered fp32 state
    __shared__ float red[2][16][4][GROWS];    // per-wave, per-16-lane partials
    __shared__ u32 cnt_sv[2];                 // monotone poller-wave counters
    __shared__ u32 cnt_red[2];                // monotone FMA-wave counters

    // ---- pre-loop: local deposit of s_0 ----
    if (tid < 256) {
        float4 a  = *(const float4*)(s0 + tid * 8);
        float4 bb = *(const float4*)(s0 + tid * 8 + 4);
        *(float4*)&sv_lds[0][tid * 8]     = a;
        *(float4*)&sv_lds[0][tid * 8 + 4] = bb;
    }
    if (tid == 0) { cnt_sv[0] = 2u; cnt_sv[1] = 0u; cnt_red[0] = 0u; cnt_red[1] = 0u; }
    if (wv == 2) __builtin_amdgcn_s_setprio(1);   // finalizer wave priority
    __syncthreads();   // one-time only

    for (int t = 0; t < T_STEPS; ++t) {
        const int par   = t & 1;
        const u32 epoch = (u32)(t >> 1) + 1u;

        // input drive for step t
        float u = 0.f;
        if (c < IN_DIM) u = inp[(size_t)t * IN_DIM + c];

        // ---- wait for sv[par] = s_t ----
        if (wv < 3) {
            while (__hip_atomic_load(&cnt_sv[par], __ATOMIC_ACQUIRE,
                                     __HIP_MEMORY_SCOPE_WORKGROUP) < 2u * epoch) {}
        } else {
            while (__hip_atomic_load(&cnt_sv[par], __ATOMIC_ACQUIRE,
                                     __HIP_MEMORY_SCOPE_WORKGROUP) < 2u * epoch)
                __builtin_amdgcn_s_sleep(1);
        }

        // ---- operands from LDS (lane-consecutive: conflict-free) ----
        float sv[KCH];
        #pragma unroll
        for (int j = 0; j < KCH; ++j) sv[j] = sv_lds[par][c + j * CSTR];

        // ---- partial matvec: 64 FMAs ----
        float acc[GROWS];
        #pragma unroll
        for (int r = 0; r < GROWS; ++r) {
            float a = 0.f;
            #pragma unroll
            for (int k = 0; k < KCH; ++k) a = fmaf(w[r][k], sv[k], a);
            acc[r] = a;
        }
        if (c < IN_DIM) {
            #pragma unroll
            for (int r = 0; r < GROWS; ++r) acc[r] = fmaf(winv[r], u, acc[r]);
        }

        // ---- 16-lane reduce via VALU DPP ----
        #pragma unroll
        for (int r = 0; r < GROWS; ++r) {
            acc[r] = dpp_add<0xB1>(acc[r]);    // quad_perm xor1
            acc[r] = dpp_add<0x4E>(acc[r]);    // quad_perm xor2
            acc[r] = dpp_add<0x141>(acc[r]);   // row_half_mirror
            acc[r] = dpp_add<0x140>(acc[r]);   // row_mirror
        }
        if ((lane & 15) < 8) {
            float v = acc[0];                  // static select acc[lane&7]
            #pragma unroll
            for (int r = 1; r < GROWS; ++r) v = ((lane & 7) == r) ? acc[r] : v;
            red[par][wv][lane >> 4][lane & 7] = v;
        }
        if (lane == 0)
            __hip_atomic_fetch_add(&cnt_red[par], 1u, __ATOMIC_RELEASE,
                                   __HIP_MEMORY_SCOPE_WORKGROUP);

        // ---- finalize on wave 2: combine 16 partials, publish FIRST ----
        if (isFin) {
            while (__hip_atomic_load(&cnt_red[par], __ATOMIC_ACQUIRE,
                                     __HIP_MEMORY_SCOPE_WORKGROUP) < 16u * epoch) {}
            const int gg = lane >> 3, rr = lane & 7;
            float pre = 0.f;
            #pragma unroll
            for (int q = 0; q < 4; ++q)
                #pragma unroll
                for (int h = 0; h < 4; ++h)
                    pre += red[par][4 * gg + q][h][rr];
            float e  = __expf(2.0f * pre);
            float th = 1.0f - 2.0f / (e + 1.0f);
            float sn = 0.9f * s_old + 0.1f * th;
            s_old = sn;
            const int j = b * BROWS + lane;
            if (t < T_STEPS - 1) {
                // pack (tag16 | bf16-RNE) and publish to interleaved slot
                u32 ub = __float_as_uint(sn);
                u32 rb = (ub + 0x7FFFu + ((ub >> 16) & 1u)) >> 16;
                u32 word = ((u32)(t + 1) << 16) | rb;
                u32* ps = buf + ((t + 1) & 1) * UNITS + (((j & 127) << 4) | (j >> 7));
                asm volatile("global_store_dword %0, %1, off sc0 sc1"
                             :: "v"(ps), "v"(word) : "memory");
            }
            out[(size_t)t * UNITS + j] = sn;
            if (t == T_STEPS - 1) out[(size_t)T_STEPS * UNITS + j] = sn;
        }

        // ---- pollers: depth-2 pipelined gather of s_{t+1} ----
        if (isPoller && t < T_STEPS - 1) {
            const int pnx = (t + 1) & 1;
            const u32 tg  = (u32)(t + 1) << 16;
            const u32* pp = buf + pnx * UNITS + p * PCH;
            u32x4 A0, A1, A2, A3, B0, B1, B2, B3;
            bool useA;
            ISSUE(A0, A1, A2, A3);
            while (true) {
                ISSUE(B0, B1, B2, B3);
                WAIT4(A0, A1, A2, A3);
                u32 ea = orx4(A0, tg) | orx4(A1, tg) | orx4(A2, tg) | orx4(A3, tg);
                if (__all((ea & 0xFFFF0000u) == 0u)) { useA = true; break; }
                ISSUE(A0, A1, A2, A3);
                WAIT4(B0, B1, B2, B3);
                u32 eb = orx4(B0, tg) | orx4(B1, tg) | orx4(B2, tg) | orx4(B3, tg);
                if (__all((eb & 0xFFFF0000u) == 0u)) { useA = false; break; }
            }
            asm volatile("s_waitcnt vmcnt(0)" ::: "memory");   // drain loser set
            if (useA) DEP(A0, A1, A2, A3); else DEP(B0, B1, B2, B3);
            if (lane == 0)
                __hip_atomic_fetch_add(&cnt_sv[pnx], 1u, __ATOMIC_RELEASE,
                                       __HIP_MEMORY_SCOPE_WORKGROUP);
        }
    }
}

extern "C" void kernel_launch(void* const* d_in, const int* in_sizes, int n_in,
                              void* d_out, int out_size, void* d_ws, size_t ws_size,
                              hipStream_t stream) {
    const float* inp = (const float*)d_in[0];   // input_sequence [4096,128]
    const float* s0  = (const float*)d_in[1];   // initial_state  [1,2048]
    const float* W   = (const float*)d_in[2];   // W   [2048,2048]
    const float* Win = (const float*)d_in[3];   // Win [2048,128]
    float* out = (float*)d_out;
    u32* buf = (u32*)d_ws;                      // 2*2048*4 = 16 KiB scratch

    esn_init<<<dim3(16), dim3(256), 0, stream>>>(buf);

    void* args[6];
    args[0] = (void*)&inp; args[1] = (void*)&s0;  args[2] = (void*)&W;
    args[3] = (void*)&Win; args[4] = (void*)&out; args[5] = (void*)&buf;
    hipLaunchCooperativeKernel((void*)esn_step, dim3(NBLK), dim3(TPB), args, 0, stream);
}

// Round 9
// 11943.722 us; speedup vs baseline: 2.0052x; 2.0052x over previous
//
#include <hip/hip_runtime.h>

#define UNITS   2048
#define IN_DIM  128
#define T_STEPS 4096
#define NBLK    64
#define TPB     1024
#define BROWS   32    // rows per block
#define GROWS   8     // rows per thread-group
#define KCH     8     // cols per thread
#define CSTR    256   // col stride between a thread's cols

typedef unsigned int u32;
typedef u32 u32x4 __attribute__((ext_vector_type(4)));
typedef u32 u32x2 __attribute__((ext_vector_type(2)));

// Reset pair tags so stale tags from a previous graph replay can never match.
// Tag 0 is never polled (first poll looks for tag 1).
__global__ void esn_init(u32x2* __restrict__ buf) {
    int i = blockIdx.x * blockDim.x + threadIdx.x;
    if (i < 2 * UNITS) { u32x2 z; z[0] = 0u; z[1] = 0u; buf[i] = z; }
}

template <int CTRL>
__device__ __forceinline__ float dpp_add(float x) {
    int y = __builtin_amdgcn_update_dpp(0, __float_as_int(x), CTRL, 0xF, 0xF, true);
    return x + __int_as_float(y);
}

__global__ void __launch_bounds__(TPB, 4) esn_step(
    const float* __restrict__ inp,   // [4096][128]
    const float* __restrict__ s0,    // [2048]
    const float* __restrict__ W,     // [2048][2048] row-major
    const float* __restrict__ Win,   // [2048][128]
    float* __restrict__ out,         // [4096*2048 + 2048]
    u32x2* __restrict__ buf)         // [2][2048] (value, step-tag) pairs
{
    const int b    = blockIdx.x;
    const int tid  = threadIdx.x;
    const int c    = tid & 255;      // col id: this thread's cols are c + 256*j
    const int g    = tid >> 8;       // row group 0..3
    const int lane = tid & 63;
    const int wv   = tid >> 6;       // wave 0..15

    // ---- W fragment: rows row0..row0+7, cols c+256*j — pinned in AGPRs ----
    // The VGPR allocator refuses to keep w[64] resident (spills to scratch ->
    // 256KB/CU/step L2 restream on the critical path). Explicit "a"-class
    // operands pin all 64 values in accumulation registers (unused otherwise).
    const int row0 = b * BROWS + g * GROWS;
    float wa[GROWS][KCH];            // each element lives in an AGPR
    #pragma unroll
    for (int r = 0; r < GROWS; ++r) {
        const float* wp = W + (size_t)(row0 + r) * UNITS + c;
        #pragma unroll
        for (int j = 0; j < KCH; ++j) {
            float tmp = wp[j * CSTR];
            asm volatile("v_accvgpr_write_b32 %0, %1"
                         : "=a"(wa[r][j]) : "v"(tmp));
        }
    }

    float winv[GROWS];
    #pragma unroll
    for (int r = 0; r < GROWS; ++r) winv[r] = 0.f;
    if (c < IN_DIM) {
        #pragma unroll
        for (int r = 0; r < GROWS; ++r)
            winv[r] = Win[(size_t)(row0 + r) * IN_DIM + c];
    }

    float s_old = (tid < BROWS) ? s0[b * BROWS + tid] : 0.f;

    __shared__ float sv_lds[2][UNITS];          // parity-buffered state vector
    __shared__ float red[2][16][4][GROWS];      // per-wave, per-row16 partials
    __shared__ u32 cnt_sv[2];                   // monotone poller-deposit counters
    __shared__ u32 cnt_red[2];                  // monotone wave-partial counters

    // ---- pre-loop: local deposit of s_0 (no comm needed for step 0) ----
    if (tid < 256) {
        float4 a  = *(const float4*)(s0 + tid * 8);
        float4 bb = *(const float4*)(s0 + tid * 8 + 4);
        *(float4*)&sv_lds[0][tid * 8]     = a;
        *(float4*)&sv_lds[0][tid * 8 + 4] = bb;
    }
    if (tid == 0) { cnt_sv[0] = 4u; cnt_sv[1] = 0u; cnt_red[0] = 0u; cnt_red[1] = 0u; }
    __syncthreads();   // one-time only

    for (int t = 0; t < T_STEPS; ++t) {
        const int par   = t & 1;
        const u32 epoch = (u32)(t >> 1) + 1u;

        // input drive for step t (issue before the spin to hide latency)
        float u = 0.f;
        if (c < IN_DIM) u = inp[(size_t)t * IN_DIM + c];

        // ---- wait for sv[par] = s_t (pollers spin tight; others back off) ----
        if (wv >= 4) {
            while (__hip_atomic_load(&cnt_sv[par], __ATOMIC_ACQUIRE,
                                     __HIP_MEMORY_SCOPE_WORKGROUP) < 4u * epoch)
                __builtin_amdgcn_s_sleep(1);
        } else {
            while (__hip_atomic_load(&cnt_sv[par], __ATOMIC_ACQUIRE,
                                     __HIP_MEMORY_SCOPE_WORKGROUP) < 4u * epoch) {}
        }

        // ---- operands from LDS (lane-consecutive: conflict-free) ----
        float sv[KCH];
        #pragma unroll
        for (int j = 0; j < KCH; ++j) sv[j] = sv_lds[par][c + j * CSTR];

        // ---- partial matvec: 64 x (accvgpr_read + fma) ----
        float acc[GROWS];
        #pragma unroll
        for (int r = 0; r < GROWS; ++r) {
            float a = 0.f;
            #pragma unroll
            for (int k = 0; k < KCH; ++k) {
                float wv_;
                asm volatile("v_accvgpr_read_b32 %0, %1"
                             : "=v"(wv_) : "a"(wa[r][k]));
                a = fmaf(wv_, sv[k], a);
            }
            acc[r] = a;
        }
        if (c < IN_DIM) {
            #pragma unroll
            for (int r = 0; r < GROWS; ++r) acc[r] = fmaf(winv[r], u, acc[r]);
        }

        // ---- reduce across 16 lanes via VALU DPP (no LDS pipe) ----
        #pragma unroll
        for (int r = 0; r < GROWS; ++r) {
            acc[r] = dpp_add<0xB1>(acc[r]);    // quad_perm xor1
            acc[r] = dpp_add<0x4E>(acc[r]);    // quad_perm xor2
            acc[r] = dpp_add<0x141>(acc[r]);   // row_half_mirror (+other quad)
            acc[r] = dpp_add<0x140>(acc[r]);   // row_mirror (+other 8)
        }
        if ((lane & 15) < 8) {
            float v = acc[0];                  // static select acc[lane&7]
            #pragma unroll
            for (int r = 1; r < GROWS; ++r) v = ((lane & 7) == r) ? acc[r] : v;
            red[par][wv][lane >> 4][lane & 7] = v;
        }
        if (lane == 0)
            __hip_atomic_fetch_add(&cnt_red[par], 1u, __ATOMIC_RELEASE,
                                   __HIP_MEMORY_SCOPE_WORKGROUP);

        // ---- finalize: 32 threads combine 16 partials, publish immediately ----
        if (tid < BROWS) {
            while (__hip_atomic_load(&cnt_red[par], __ATOMIC_ACQUIRE,
                                     __HIP_MEMORY_SCOPE_WORKGROUP) < 16u * epoch) {}
            const int gg = tid >> 3, rr = tid & 7;
            float pre = 0.f;
            #pragma unroll
            for (int q = 0; q < 4; ++q)
                #pragma unroll
                for (int h = 0; h < 4; ++h)
                    pre += red[par][4 * gg + q][h][rr];
            float e  = __expf(2.0f * pre);
            float th = 1.0f - 2.0f / (e + 1.0f);
            float sn = 0.9f * s_old + 0.1f * th;
            s_old = sn;
            const int j = b * BROWS + tid;
            if (t < T_STEPS - 1) {
                u32x2 vt; vt[0] = __float_as_uint(sn); vt[1] = (u32)(t + 1);
                u32x2* ps = buf + ((t + 1) & 1) * UNITS + j;
                asm volatile("global_store_dwordx2 %0, %1, off sc0 sc1"
                             :: "v"(ps), "v"(vt) : "memory");
            }
            out[(size_t)t * UNITS + j] = sn;
            if (t == T_STEPS - 1) out[(size_t)T_STEPS * UNITS + j] = sn;
        }

        // ---- pollers gather s_{t+1} for the next iteration (direct 64B poll) ----
        if (wv < 4 && t < T_STEPS - 1) {
            const int pnx = (t + 1) & 1;
            const u32 tag = (u32)(t + 1);
            const u32x2* pp = buf + pnx * UNITS + tid * KCH;
            u32x4 A, B, C, D;
            while (true) {
                asm volatile(
                    "global_load_dwordx4 %0, %4, off sc0 sc1\n\t"
                    "global_load_dwordx4 %1, %4, off offset:16 sc0 sc1\n\t"
                    "global_load_dwordx4 %2, %4, off offset:32 sc0 sc1\n\t"
                    "global_load_dwordx4 %3, %4, off offset:48 sc0 sc1\n\t"
                    "s_waitcnt vmcnt(0)"
                    : "=v"(A), "=v"(B), "=v"(C), "=v"(D)
                    : "v"(pp)
                    : "memory");
                bool ok = (A[1] == tag) & (A[3] == tag) & (B[1] == tag) & (B[3] == tag)
                        & (C[1] == tag) & (C[3] == tag) & (D[1] == tag) & (D[3] == tag);
                if (ok) break;
            }
            float4 v0, v1;
            v0.x = __uint_as_float(A[0]); v0.y = __uint_as_float(A[2]);
            v0.z = __uint_as_float(B[0]); v0.w = __uint_as_float(B[2]);
            v1.x = __uint_as_float(C[0]); v1.y = __uint_as_float(C[2]);
            v1.z = __uint_as_float(D[0]); v1.w = __uint_as_float(D[2]);
            float4* dst = (float4*)&sv_lds[pnx][tid * KCH];
            dst[0] = v0; dst[1] = v1;
            if (lane == 0)
                __hip_atomic_fetch_add(&cnt_sv[pnx], 1u, __ATOMIC_RELEASE,
                                       __HIP_MEMORY_SCOPE_WORKGROUP);
        }
    }
}

extern "C" void kernel_launch(void* const* d_in, const int* in_sizes, int n_in,
                              void* d_out, int out_size, void* d_ws, size_t ws_size,
                              hipStream_t stream) {
    const float* inp = (const float*)d_in[0];   // input_sequence [4096,128]
    const float* s0  = (const float*)d_in[1];   // initial_state  [1,2048]
    const float* W   = (const float*)d_in[2];   // W   [2048,2048]
    const float* Win = (const float*)d_in[3];   // Win [2048,128]
    float* out = (float*)d_out;
    u32x2* buf = (u32x2*)d_ws;                  // 2*2048*8 = 32 KiB scratch

    esn_init<<<dim3(16), dim3(256), 0, stream>>>(buf);

    void* args[6];
    args[0] = (void*)&inp; args[1] = (void*)&s0;  args[2] = (void*)&W;
    args[3] = (void*)&Win; args[4] = (void*)&out; args[5] = (void*)&buf;
    hipLaunchCooperativeKernel((void*)esn_step, dim3(NBLK), dim3(TPB), args, 0, stream);
}

// Round 10
// 10080.530 us; speedup vs baseline: 2.3758x; 1.1848x over previous
//
#include <hip/hip_runtime.h>

#define UNITS   2048
#define IN_DIM  128
#define T_STEPS 4096
#define NBLK    64
#define TPB     512
#define BROWS   32    // rows per block
#define KCH     8     // units per poller thread
#define KTILES  68    // (2048 + 128) / 32 extended K tiles
#define KHALF   34    // K tiles per compute wave

typedef unsigned int u32;
typedef u32 u32x4 __attribute__((ext_vector_type(4)));
typedef u32 u32x2 __attribute__((ext_vector_type(2)));
typedef short short8 __attribute__((ext_vector_type(8)));
typedef __bf16 bf16x8 __attribute__((ext_vector_type(8)));
typedef float f32x4 __attribute__((ext_vector_type(4)));

// Reset pair tags so stale tags from a previous graph replay can never match.
__global__ void esn_init(u32x2* __restrict__ buf) {
    int i = blockIdx.x * blockDim.x + threadIdx.x;
    if (i < 2 * UNITS) { u32x2 z; z[0] = 0u; z[1] = 0u; buf[i] = z; }
}

__device__ __forceinline__ unsigned short f2bf(float f) {   // RNE float->bf16 bits
    u32 x = __float_as_uint(f);
    return (unsigned short)((x + 0x7FFFu + ((x >> 16) & 1u)) >> 16);
}

__global__ void __launch_bounds__(TPB) esn_step(
    const float* __restrict__ inp,   // [4096][128]
    const float* __restrict__ s0,    // [2048]
    const float* __restrict__ W,     // [2048][2048] row-major
    const float* __restrict__ Win,   // [2048][128]
    float* __restrict__ out,         // [4096*2048 + 2048]
    u32x2* __restrict__ buf)         // [2][2048] (value, step-tag) pairs
{
    const int b    = blockIdx.x;
    const int tid  = threadIdx.x;
    const int lane = tid & 63;
    const int wv   = tid >> 6;       // wave 0..7: 0-3 poll, 4-7 MFMA
    const int h8   = (lane >> 4) * 8;

    __shared__ unsigned short s_bf16[2][KTILES * 32];  // bf16 [state | input] per parity
    __shared__ float red[2][4][16];                    // per-compute-wave C partials
    __shared__ float s_state[BROWS];                   // fp32 running state (own rows)
    __shared__ u32 cnt_sv[2];                          // poller-wave deposit counters
    __shared__ u32 cnt_mm[2];                          // compute-wave done counters

    // ---- compute waves: preload W_ext fragments as bf16 (register-resident) ----
    bf16x8 afr[KHALF];
    const int m  = wv - 4;                 // compute-wave id 0..3 (valid if wv>=4)
    const int kb = (m & 1) * KHALF;        // K-tile base (0 or 34)
    if (wv >= 4) {
        const int arow = b * BROWS + (m >> 1) * 16 + (lane & 15);
        #pragma unroll
        for (int tt = 0; tt < KHALF; ++tt) {
            const int kbase = (kb + tt) * 32 + h8;
            short8 st;
            #pragma unroll
            for (int r = 0; r < 8; ++r) {
                const int col = kbase + r;
                float v = (col < UNITS) ? W[(size_t)arow * UNITS + col]
                                        : Win[(size_t)arow * IN_DIM + (col - UNITS)];
                st[r] = (short)f2bf(v);
            }
            afr[tt] = *(bf16x8*)&st;
        }
    }

    // ---- pre-loop: deposit s_0 and u_0, init state/counters ----
    if (tid < 256) {                       // 256 pollers: units tid*8..tid*8+7
        float4 a  = *(const float4*)(s0 + tid * 8);
        float4 bb = *(const float4*)(s0 + tid * 8 + 4);
        short8 st;
        st[0] = (short)f2bf(a.x);  st[1] = (short)f2bf(a.y);
        st[2] = (short)f2bf(a.z);  st[3] = (short)f2bf(a.w);
        st[4] = (short)f2bf(bb.x); st[5] = (short)f2bf(bb.y);
        st[6] = (short)f2bf(bb.z); st[7] = (short)f2bf(bb.w);
        *(short8*)&s_bf16[0][tid * 8] = st;
    }
    if (tid < 32) {
        s_state[tid] = s0[b * BROWS + tid];
        float4 uf = *(const float4*)(inp + tid * 4);
        unsigned short* d = &s_bf16[0][UNITS + tid * 4];
        d[0] = f2bf(uf.x); d[1] = f2bf(uf.y); d[2] = f2bf(uf.z); d[3] = f2bf(uf.w);
    }
    if (tid == 0) { cnt_sv[0] = 4u; cnt_sv[1] = 0u; cnt_mm[0] = 0u; cnt_mm[1] = 0u; }
    __syncthreads();   // one-time only

    for (int t = 0; t < T_STEPS; ++t) {
        const int par   = t & 1;
        const u32 epoch = (u32)(t >> 1) + 1u;

        if (wv >= 4) {
            // ---- wait for state+input of step t ----
            while (__hip_atomic_load(&cnt_sv[par], __ATOMIC_ACQUIRE,
                                     __HIP_MEMORY_SCOPE_WORKGROUP) < 4u * epoch) {}

            // ---- 34 MFMAs: rows (m>>1)*16..+15, K-tiles kb..kb+33 ----
            f32x4 acc = {0.f, 0.f, 0.f, 0.f};
            #pragma unroll
            for (int tt = 0; tt < KHALF; ++tt) {
                bf16x8 bfr = *(const bf16x8*)&s_bf16[par][(kb + tt) * 32 + h8];
                acc = __builtin_amdgcn_mfma_f32_16x16x32_bf16(afr[tt], bfr, acc, 0, 0, 0);
            }
            // C layout (verified): col=lane&15, row=(lane>>4)*4+reg. Col 0 lanes
            // carry all 16 rows (replicated-B makes all cols identical).
            if ((lane & 15) == 0)
                *(f32x4*)&red[par][m][(lane >> 4) * 4] = acc;

            u32 rtn = 0;
            if (lane == 0)
                rtn = __hip_atomic_fetch_add(&cnt_mm[par], 1u, __ATOMIC_ACQ_REL,
                                             __HIP_MEMORY_SCOPE_WORKGROUP);
            rtn = __shfl(rtn, 0);

            // ---- last-finishing wave finalizes immediately (no wake hop) ----
            if (rtn == 4u * epoch - 1u) {
                if (lane < BROWS) {
                    const int rt = lane >> 4;
                    float pre = red[par][2 * rt][lane & 15]
                              + red[par][2 * rt + 1][lane & 15];
                    float e  = __expf(2.0f * pre);
                    float th = 1.0f - 2.0f / (e + 1.0f);
                    float sn = 0.9f * s_state[lane] + 0.1f * th;
                    s_state[lane] = sn;
                    const int j = b * BROWS + lane;
                    if (t < T_STEPS - 1) {
                        u32x2 vt; vt[0] = __float_as_uint(sn); vt[1] = (u32)(t + 1);
                        u32x2* ps = buf + ((t + 1) & 1) * UNITS + j;
                        asm volatile("global_store_dwordx2 %0, %1, off sc0 sc1"
                                     :: "v"(ps), "v"(vt) : "memory");
                    }
                    out[(size_t)t * UNITS + j] = sn;
                    if (t == T_STEPS - 1) out[(size_t)T_STEPS * UNITS + j] = sn;
                }
            }
        } else if (t < T_STEPS - 1) {
            // ---- pollers: gather s_{t+1}; wave 0 also loads u_{t+1} ----
            float4 uf;
            if (wv == 0 && lane < 32)
                uf = *(const float4*)(inp + (size_t)(t + 1) * IN_DIM + lane * 4);

            const int pnx = (t + 1) & 1;
            const u32 tag = (u32)(t + 1);
            const u32x2* pp = buf + pnx * UNITS + tid * KCH;
            u32x4 A, B, C, D;
            while (true) {
                asm volatile(
                    "global_load_dwordx4 %0, %4, off sc0 sc1\n\t"
                    "global_load_dwordx4 %1, %4, off offset:16 sc0 sc1\n\t"
                    "global_load_dwordx4 %2, %4, off offset:32 sc0 sc1\n\t"
                    "global_load_dwordx4 %3, %4, off offset:48 sc0 sc1\n\t"
                    "s_waitcnt vmcnt(0)"
                    : "=v"(A), "=v"(B), "=v"(C), "=v"(D)
                    : "v"(pp)
                    : "memory");
                bool ok = (A[1] == tag) & (A[3] == tag) & (B[1] == tag) & (B[3] == tag)
                        & (C[1] == tag) & (C[3] == tag) & (D[1] == tag) & (D[3] == tag);
                if (ok) break;
            }
            short8 st;
            st[0] = (short)f2bf(__uint_as_float(A[0]));
            st[1] = (short)f2bf(__uint_as_float(A[2]));
            st[2] = (short)f2bf(__uint_as_float(B[0]));
            st[3] = (short)f2bf(__uint_as_float(B[2]));
            st[4] = (short)f2bf(__uint_as_float(C[0]));
            st[5] = (short)f2bf(__uint_as_float(C[2]));
            st[6] = (short)f2bf(__uint_as_float(D[0]));
            st[7] = (short)f2bf(__uint_as_float(D[2]));
            *(short8*)&s_bf16[pnx][tid * 8] = st;

            if (wv == 0 && lane < 32) {
                unsigned short* d = &s_bf16[pnx][UNITS + lane * 4];
                d[0] = f2bf(uf.x); d[1] = f2bf(uf.y);
                d[2] = f2bf(uf.z); d[3] = f2bf(uf.w);
            }
            if (lane == 0)
                __hip_atomic_fetch_add(&cnt_sv[pnx], 1u, __ATOMIC_RELEASE,
                                       __HIP_MEMORY_SCOPE_WORKGROUP);
        }
    }
}

extern "C" void kernel_launch(void* const* d_in, const int* in_sizes, int n_in,
                              void* d_out, int out_size, void* d_ws, size_t ws_size,
                              hipStream_t stream) {
    const float* inp = (const float*)d_in[0];   // input_sequence [4096,128]
    const float* s0  = (const float*)d_in[1];   // initial_state  [1,2048]
    const float* W   = (const float*)d_in[2];   // W   [2048,2048]
    const float* Win = (const float*)d_in[3];   // Win [2048,128]
    float* out = (float*)d_out;
    u32x2* buf = (u32x2*)d_ws;                  // 2*2048*8 = 32 KiB scratch

    esn_init<<<dim3(16), dim3(256), 0, stream>>>(buf);

    void* args[6];
    args[0] = (void*)&inp; args[1] = (void*)&s0;  args[2] = (void*)&W;
    args[3] = (void*)&Win; args[4] = (void*)&out; args[5] = (void*)&buf;
    hipLaunchCooperativeKernel((void*)esn_step, dim3(NBLK), dim3(TPB), args, 0, stream);
}

// Round 11
// 8679.526 us; speedup vs baseline: 2.7593x; 1.1614x over previous
//
#include <hip/hip_runtime.h>

#define UNITS   2048
#define IN_DIM  128
#define T_STEPS 4096
#define NBLK    64
#define TPB     512
#define BROWS   32    // rows per block

typedef unsigned int u32;
typedef u32 u32x4 __attribute__((ext_vector_type(4)));
typedef short short8 __attribute__((ext_vector_type(8)));
typedef __bf16 bf16x8 __attribute__((ext_vector_type(8)));
typedef float f32x4 __attribute__((ext_vector_type(4)));

// Zero comm words each call: tag 0 never matches (first polled tag is 1).
__global__ void esn_init(u32* __restrict__ buf) {
    int i = blockIdx.x * blockDim.x + threadIdx.x;
    if (i < 2 * UNITS) buf[i] = 0u;
}

__device__ __forceinline__ unsigned short f2bf(float f) {   // RNE float->bf16 bits
    u32 x = __float_as_uint(f);
    return (unsigned short)((x + 0x7FFFu + ((x >> 16) & 1u)) >> 16);
}

__global__ void __launch_bounds__(TPB, 2) esn_step(
    const float* __restrict__ inp,   // [4096][128]
    const float* __restrict__ s0,    // [2048]
    const float* __restrict__ W,     // [2048][2048] row-major
    const float* __restrict__ Win,   // [2048][128]
    float* __restrict__ out,         // [4096*2048 + 2048]
    u32* __restrict__ buf)           // [2][2048] packed (tag16|bf16) words
{
    const int b    = blockIdx.x;
    const int tid  = threadIdx.x;
    const int lane = tid & 63;
    const int wv   = tid >> 6;       // waves 0-3 poll, 4-7 MFMA
    const int h8   = (lane >> 4) * 8;

    __shared__ unsigned short s_bf16[2][UNITS];  // bf16 state per parity
    __shared__ float red[2][4][16];              // per-compute-wave C column
    __shared__ float s_state[BROWS];             // fp32 running state (own rows)
    __shared__ u32 cnt_w[2][4];                  // per poller-wave deposit counters
    __shared__ u32 cnt_mm[2];                    // compute-wave done counters

    // ---- compute waves: static A fragments (32 state tiles + 2 input tiles) ----
    const int m    = wv - 4;             // compute-wave id 0..3 (valid if wv>=4)
    const int half = m & 1;              // K half: 0 -> units 0-1023, 1 -> 1024-2047
    bf16x8 afr[34];
    if (wv >= 4) {
        const int arow = b * BROWS + (m >> 1) * 16 + (lane & 15);
        #pragma unroll
        for (int tt = 0; tt < 32; ++tt) {
            const int kbase = (half * 32 + tt) * 32 + h8;
            short8 st;
            #pragma unroll
            for (int r = 0; r < 8; ++r)
                st[r] = (short)f2bf(W[(size_t)arow * UNITS + kbase + r]);
            afr[tt] = *(bf16x8*)&st;
        }
        #pragma unroll
        for (int it = 0; it < 2; ++it) {
            const int kbase = half * 64 + it * 32 + h8;
            short8 st;
            #pragma unroll
            for (int r = 0; r < 8; ++r)
                st[r] = (short)f2bf(Win[(size_t)arow * IN_DIM + kbase + r]);
            afr[32 + it] = *(bf16x8*)&st;
        }
    }

    // ---- pre-loop: deposit bf16(s_0), init state/counters ----
    if (tid < 256) {
        float4 a  = *(const float4*)(s0 + tid * 8);
        float4 bb = *(const float4*)(s0 + tid * 8 + 4);
        short8 st;
        st[0] = (short)f2bf(a.x);  st[1] = (short)f2bf(a.y);
        st[2] = (short)f2bf(a.z);  st[3] = (short)f2bf(a.w);
        st[4] = (short)f2bf(bb.x); st[5] = (short)f2bf(bb.y);
        st[6] = (short)f2bf(bb.z); st[7] = (short)f2bf(bb.w);
        *(short8*)&s_bf16[0][tid * 8] = st;
    }
    if (tid < BROWS) s_state[tid] = s0[b * BROWS + tid];
    if (tid < 4)  { cnt_w[0][tid] = 1u; cnt_w[1][tid] = 0u; }
    if (tid == 0) { cnt_mm[0] = 0u; cnt_mm[1] = 0u; }
    __syncthreads();   // one-time only

    for (int t = 0; t < T_STEPS; ++t) {
        const int par   = t & 1;
        const u32 epoch = (u32)(t >> 1) + 1u;

        if (wv >= 4) {
            // ---- build input B fragments for step t (independent of state) ----
            const float* ip = inp + (size_t)t * IN_DIM + half * 64;
            float4 i0a = *(const float4*)(ip + h8);
            float4 i0b = *(const float4*)(ip + h8 + 4);
            float4 i1a = *(const float4*)(ip + 32 + h8);
            float4 i1b = *(const float4*)(ip + 32 + h8 + 4);
            short8 s0i, s1i;
            s0i[0] = (short)f2bf(i0a.x); s0i[1] = (short)f2bf(i0a.y);
            s0i[2] = (short)f2bf(i0a.z); s0i[3] = (short)f2bf(i0a.w);
            s0i[4] = (short)f2bf(i0b.x); s0i[5] = (short)f2bf(i0b.y);
            s0i[6] = (short)f2bf(i0b.z); s0i[7] = (short)f2bf(i0b.w);
            s1i[0] = (short)f2bf(i1a.x); s1i[1] = (short)f2bf(i1a.y);
            s1i[2] = (short)f2bf(i1a.z); s1i[3] = (short)f2bf(i1a.w);
            s1i[4] = (short)f2bf(i1b.x); s1i[5] = (short)f2bf(i1b.y);
            s1i[6] = (short)f2bf(i1b.z); s1i[7] = (short)f2bf(i1b.w);

            // ---- input MFMAs first (before the wait): two independent chains ----
            f32x4 a0 = {0.f, 0.f, 0.f, 0.f}, a1 = {0.f, 0.f, 0.f, 0.f};
            a0 = __builtin_amdgcn_mfma_f32_16x16x32_bf16(afr[32], *(bf16x8*)&s0i, a0, 0, 0, 0);
            a1 = __builtin_amdgcn_mfma_f32_16x16x32_bf16(afr[33], *(bf16x8*)&s1i, a1, 0, 0, 0);

            // ---- wait only for OUR K-half (2 of 4 poller waves) ----
            const int hw = half * 2;
            while (__hip_atomic_load(&cnt_w[par][hw], __ATOMIC_ACQUIRE,
                                     __HIP_MEMORY_SCOPE_WORKGROUP) < epoch ||
                   __hip_atomic_load(&cnt_w[par][hw + 1], __ATOMIC_ACQUIRE,
                                     __HIP_MEMORY_SCOPE_WORKGROUP) < epoch) {}

            // ---- 32 state MFMAs in two independent 16-deep chains ----
            #pragma unroll
            for (int tt = 0; tt < 16; ++tt) {
                bf16x8 b0 = *(const bf16x8*)&s_bf16[par][(half * 32 + 2 * tt) * 32 + h8];
                bf16x8 b1 = *(const bf16x8*)&s_bf16[par][(half * 32 + 2 * tt + 1) * 32 + h8];
                a0 = __builtin_amdgcn_mfma_f32_16x16x32_bf16(afr[2 * tt],     b0, a0, 0, 0, 0);
                a1 = __builtin_amdgcn_mfma_f32_16x16x32_bf16(afr[2 * tt + 1], b1, a1, 0, 0, 0);
            }
            f32x4 acc = a0 + a1;

            // C layout: col=lane&15, row=(lane>>4)*4+reg; B replicated -> col 0 only
            if ((lane & 15) == 0)
                *(f32x4*)&red[par][m][(lane >> 4) * 4] = acc;

            u32 rtn = 0;
            if (lane == 0)
                rtn = __hip_atomic_fetch_add(&cnt_mm[par], 1u, __ATOMIC_ACQ_REL,
                                             __HIP_MEMORY_SCOPE_WORKGROUP);
            rtn = __shfl(rtn, 0);

            // ---- last-finishing wave finalizes immediately ----
            if (rtn == 4u * epoch - 1u && lane < BROWS) {
                const int rg = lane >> 4;
                float pre = red[par][2 * rg][lane & 15]
                          + red[par][2 * rg + 1][lane & 15];
                float e  = __expf(2.0f * pre);
                float th = 1.0f - 2.0f / (e + 1.0f);
                float sn = 0.9f * s_state[lane] + 0.1f * th;
                s_state[lane] = sn;
                const int j = b * BROWS + lane;
                if (t < T_STEPS - 1) {
                    u32 word = ((u32)(t + 1) << 16) | (u32)f2bf(sn);
                    u32* ps = buf + ((t + 1) & 1) * UNITS + j;   // contiguous 128B/block
                    asm volatile("global_store_dword %0, %1, off sc0 sc1"
                                 :: "v"(ps), "v"(word) : "memory");
                }
                out[(size_t)t * UNITS + j] = sn;
                if (t == T_STEPS - 1) out[(size_t)T_STEPS * UNITS + j] = sn;
            }
        } else if (t < T_STEPS - 1) {
            // ---- pollers: 8 packed words (32B) per thread, direct poll ----
            const int pnx = (t + 1) & 1;
            const u32 tag = (u32)(t + 1);
            const u32* pp = buf + pnx * UNITS + tid * 8;
            u32x4 A, B;
            while (true) {
                asm volatile(
                    "global_load_dwordx4 %0, %2, off sc0 sc1\n\t"
                    "global_load_dwordx4 %1, %2, off offset:16 sc0 sc1\n\t"
                    "s_waitcnt vmcnt(0)"
                    : "=v"(A), "=v"(B)
                    : "v"(pp)
                    : "memory");
                bool ok = ((A[0] >> 16) == tag) & ((A[1] >> 16) == tag)
                        & ((A[2] >> 16) == tag) & ((A[3] >> 16) == tag)
                        & ((B[0] >> 16) == tag) & ((B[1] >> 16) == tag)
                        & ((B[2] >> 16) == tag) & ((B[3] >> 16) == tag);
                if (ok) break;
            }
            short8 st;
            st[0] = (short)(A[0] & 0xFFFFu); st[1] = (short)(A[1] & 0xFFFFu);
            st[2] = (short)(A[2] & 0xFFFFu); st[3] = (short)(A[3] & 0xFFFFu);
            st[4] = (short)(B[0] & 0xFFFFu); st[5] = (short)(B[1] & 0xFFFFu);
            st[6] = (short)(B[2] & 0xFFFFu); st[7] = (short)(B[3] & 0xFFFFu);
            *(short8*)&s_bf16[pnx][tid * 8] = st;
            if (lane == 0)
                __hip_atomic_fetch_add(&cnt_w[pnx][wv], 1u, __ATOMIC_RELEASE,
                                       __HIP_MEMORY_SCOPE_WORKGROUP);
        }
    }
}

extern "C" void kernel_launch(void* const* d_in, const int* in_sizes, int n_in,
                              void* d_out, int out_size, void* d_ws, size_t ws_size,
                              hipStream_t stream) {
    const float* inp = (const float*)d_in[0];   // input_sequence [4096,128]
    const float* s0  = (const float*)d_in[1];   // initial_state  [1,2048]
    const float* W   = (const float*)d_in[2];   // W   [2048,2048]
    const float* Win = (const float*)d_in[3];   // Win [2048,128]
    float* out = (float*)d_out;
    u32* buf = (u32*)d_ws;                      // 2*2048*4 = 16 KiB scratch

    esn_init<<<dim3(16), dim3(256), 0, stream>>>(buf);

    void* args[6];
    args[0] = (void*)&inp; args[1] = (void*)&s0;  args[2] = (void*)&W;
    args[3] = (void*)&Win; args[4] = (void*)&out; args[5] = (void*)&buf;
    hipLaunchCooperativeKernel((void*)esn_step, dim3(NBLK), dim3(TPB), args, 0, stream);
}

// Round 12
// 5939.466 us; speedup vs baseline: 4.0323x; 1.4613x over previous
//
#include <hip/hip_runtime.h>

#define UNITS   2048
#define IN_DIM  128
#define T_STEPS 4096
#define NBLK    64
#define TPB     512
#define BROWS   32    // rows per block

typedef unsigned int u32;
typedef u32 u32x4 __attribute__((ext_vector_type(4)));
typedef u32 u32x2v __attribute__((ext_vector_type(2)));
typedef short short8 __attribute__((ext_vector_type(8)));
typedef __bf16 bf16x8 __attribute__((ext_vector_type(8)));
typedef float f32x4 __attribute__((ext_vector_type(4)));

// Zero comm words each call: tag 0 never matches (first polled tag is 1).
__global__ void esn_init(u32* __restrict__ buf) {
    int i = blockIdx.x * blockDim.x + threadIdx.x;
    if (i < 2 * UNITS) buf[i] = 0u;
}

__device__ __forceinline__ unsigned short f2bf(float f) {   // RNE float->bf16 bits
    u32 x = __float_as_uint(f);
    return (unsigned short)((x + 0x7FFFu + ((x >> 16) & 1u)) >> 16);
}

__global__ void __launch_bounds__(TPB, 2) esn_step(
    const float* __restrict__ inp,   // [4096][128]
    const float* __restrict__ s0,    // [2048]
    const float* __restrict__ W,     // [2048][2048] row-major
    const float* __restrict__ Win,   // [2048][128]
    float* __restrict__ out,         // [4096*2048 + 2048]
    u32* __restrict__ buf)           // [2][2048] packed (tag16|bf16) words
{
    const int b    = blockIdx.x;
    const int tid  = threadIdx.x;
    const int lane = tid & 63;
    const int wv   = tid >> 3 >> 3;  // == tid >> 6, wave 0..7 (all symmetric)
    const int h8   = (lane >> 4) * 8;
    const int colr = lane & 15;

    __shared__ unsigned short sB[UNITS];     // bf16 state; slice [256w,256w+256) PRIVATE to wave w
    __shared__ float red[2][8][2][16];       // per-wave C partials (parity, wave, row-tile, row)
    __shared__ float s_state[BROWS];         // fp32 running state (own rows)
    __shared__ u32 cnt_mm[2];                // compute-done counters

    // ---- static A fragments: wave w covers K-slice [256w, 256w+256), all 32 rows ----
    const int rbase = b * BROWS;
    bf16x8 a0[8], a1[8];                     // row-tile 0 (rows 0-15), row-tile 1 (16-31)
    #pragma unroll
    for (int tt = 0; tt < 8; ++tt) {
        const int kb = wv * 256 + tt * 32 + h8;
        short8 t0, t1;
        #pragma unroll
        for (int j = 0; j < 8; ++j) {
            t0[j] = (short)f2bf(W[(size_t)(rbase + colr) * UNITS + kb + j]);
            t1[j] = (short)f2bf(W[(size_t)(rbase + 16 + colr) * UNITS + kb + j]);
        }
        a0[tt] = *(bf16x8*)&t0;
        a1[tt] = *(bf16x8*)&t1;
    }
    bf16x8 ain0 = {}, ain1 = {};             // input A tiles (waves 0-3 only)
    const bool hasIn = (wv < 4);
    if (hasIn) {
        const int kb = wv * 32 + h8;
        short8 t0, t1;
        #pragma unroll
        for (int j = 0; j < 8; ++j) {
            t0[j] = (short)f2bf(Win[(size_t)(rbase + colr) * IN_DIM + kb + j]);
            t1[j] = (short)f2bf(Win[(size_t)(rbase + 16 + colr) * IN_DIM + kb + j]);
        }
        ain0 = *(bf16x8*)&t0;
        ain1 = *(bf16x8*)&t1;
    }

    // ---- pre-loop: deposit bf16(s_0) into own slice, init state/counters ----
    {
        float4 v = *(const float4*)(s0 + tid * 4);
        u32x2v pk;
        pk[0] = (u32)f2bf(v.x) | ((u32)f2bf(v.y) << 16);
        pk[1] = (u32)f2bf(v.z) | ((u32)f2bf(v.w) << 16);
        *(u32x2v*)&sB[tid * 4] = pk;
    }
    if (tid < BROWS) s_state[tid] = s0[rbase + tid];
    if (tid == 0) { cnt_mm[0] = 0u; cnt_mm[1] = 0u; }
    __syncthreads();   // one-time only

    for (int t = 0; t < T_STEPS; ++t) {
        const int par   = t & 1;
        const u32 epoch = (u32)(t >> 1) + 1u;
        const u32 tag   = (u32)t;

        // ---- issue own poll first (16B covers this lane's 4 units) ----
        const u32* pp = buf + par * UNITS + tid * 4;
        u32x4 A;
        if (t > 0)
            asm volatile("global_load_dwordx4 %0, %1, off sc0 sc1"
                         : "=v"(A) : "v"(pp) : "memory");

        // ---- input loads overlap the first poll RTT ----
        float4 iA, iB;
        if (hasIn) {
            const float* ip = inp + (size_t)t * IN_DIM + wv * 32 + h8;
            iA = *(const float4*)ip;
            iB = *(const float4*)(ip + 4);
        }

        // ---- spin: detect own 4 tags, redeposit into wave-private LDS slice ----
        if (t > 0) {
            while (true) {
                asm volatile("s_waitcnt vmcnt(0)" : "+v"(A) :: "memory");
                bool ok = ((A[0] >> 16) == tag) & ((A[1] >> 16) == tag)
                        & ((A[2] >> 16) == tag) & ((A[3] >> 16) == tag);
                if (ok) break;
                asm volatile("global_load_dwordx4 %0, %1, off sc0 sc1"
                             : "=v"(A) : "v"(pp) : "memory");
            }
            u32x2v pk;
            pk[0] = (A[0] & 0xFFFFu) | (A[1] << 16);
            pk[1] = (A[2] & 0xFFFFu) | (A[3] << 16);
            *(u32x2v*)&sB[tid * 4] = pk;     // same-wave write -> same-wave read: no barrier
        }

        // ---- MFMAs: 4 independent chains; input tiles first ----
        f32x4 c0a = {0.f,0.f,0.f,0.f}, c0b = {0.f,0.f,0.f,0.f};
        f32x4 c1a = {0.f,0.f,0.f,0.f}, c1b = {0.f,0.f,0.f,0.f};
        if (hasIn) {
            short8 si;
            si[0] = (short)f2bf(iA.x); si[1] = (short)f2bf(iA.y);
            si[2] = (short)f2bf(iA.z); si[3] = (short)f2bf(iA.w);
            si[4] = (short)f2bf(iB.x); si[5] = (short)f2bf(iB.y);
            si[6] = (short)f2bf(iB.z); si[7] = (short)f2bf(iB.w);
            bf16x8 bin = *(bf16x8*)&si;
            c0b = __builtin_amdgcn_mfma_f32_16x16x32_bf16(ain0, bin, c0b, 0, 0, 0);
            c1b = __builtin_amdgcn_mfma_f32_16x16x32_bf16(ain1, bin, c1b, 0, 0, 0);
        }
        #pragma unroll
        for (int tt = 0; tt < 8; ++tt) {
            bf16x8 bb = *(const bf16x8*)&sB[wv * 256 + tt * 32 + h8];
            if (tt & 1) {
                c0b = __builtin_amdgcn_mfma_f32_16x16x32_bf16(a0[tt], bb, c0b, 0, 0, 0);
                c1b = __builtin_amdgcn_mfma_f32_16x16x32_bf16(a1[tt], bb, c1b, 0, 0, 0);
            } else {
                c0a = __builtin_amdgcn_mfma_f32_16x16x32_bf16(a0[tt], bb, c0a, 0, 0, 0);
                c1a = __builtin_amdgcn_mfma_f32_16x16x32_bf16(a1[tt], bb, c1a, 0, 0, 0);
            }
        }
        f32x4 acc0 = c0a + c0b, acc1 = c1a + c1b;

        // ---- C partials: col-0 lanes carry all rows (B replicated across cols) ----
        if (colr == 0) {
            *(f32x4*)&red[par][wv][0][(lane >> 4) * 4] = acc0;
            *(f32x4*)&red[par][wv][1][(lane >> 4) * 4] = acc1;
        }
        u32 rtn = 0;
        if (lane == 0)
            rtn = __hip_atomic_fetch_add(&cnt_mm[par], 1u, __ATOMIC_ACQ_REL,
                                         __HIP_MEMORY_SCOPE_WORKGROUP);
        rtn = __shfl(rtn, 0);

        // ---- last-finishing wave finalizes + publishes immediately ----
        if (rtn == 8u * epoch - 1u && lane < BROWS) {
            const int rt = lane >> 4, rr = lane & 15;
            float pre = 0.f;
            #pragma unroll
            for (int w8 = 0; w8 < 8; ++w8) pre += red[par][w8][rt][rr];
            float e  = __expf(2.0f * pre);
            float th = 1.0f - 2.0f / (e + 1.0f);
            float sn = 0.9f * s_state[lane] + 0.1f * th;
            s_state[lane] = sn;
            const int j = rbase + lane;
            if (t < T_STEPS - 1) {
                u32 word = ((u32)(t + 1) << 16) | (u32)f2bf(sn);
                u32* ps = buf + ((t + 1) & 1) * UNITS + j;   // contiguous 128B/block
                asm volatile("global_store_dword %0, %1, off sc0 sc1"
                             :: "v"(ps), "v"(word) : "memory");
            }
            out[(size_t)t * UNITS + j] = sn;
            if (t == T_STEPS - 1) out[(size_t)T_STEPS * UNITS + j] = sn;
        }
    }
}

extern "C" void kernel_launch(void* const* d_in, const int* in_sizes, int n_in,
                              void* d_out, int out_size, void* d_ws, size_t ws_size,
                              hipStream_t stream) {
    const float* inp = (const float*)d_in[0];   // input_sequence [4096,128]
    const float* s0  = (const float*)d_in[1];   // initial_state  [1,2048]
    const float* W   = (const float*)d_in[2];   // W   [2048,2048]
    const float* Win = (const float*)d_in[3];   // Win [2048,128]
    float* out = (float*)d_out;
    u32* buf = (u32*)d_ws;                      // 2*2048*4 = 16 KiB scratch

    esn_init<<<dim3(16), dim3(256), 0, stream>>>(buf);

    void* args[6];
    args[0] = (void*)&inp; args[1] = (void*)&s0;  args[2] = (void*)&W;
    args[3] = (void*)&Win; args[4] = (void*)&out; args[5] = (void*)&buf;
    hipLaunchCooperativeKernel((void*)esn_step, dim3(NBLK), dim3(TPB), args, 0, stream);
}